// Round 3
// baseline (656.816 us; speedup 1.0000x reference)
//
#include <hip/hip_runtime.h>
#include <hip/hip_bf16.h>

#define T_ 128
#define N_ 256
#define L_ 256
#define H_ 256
#define COND_ 64

typedef __bf16 bf8_t __attribute__((ext_vector_type(8)));
typedef float f32x4 __attribute__((ext_vector_type(4)));

__device__ __forceinline__ float b2f(unsigned short s) {
    union { unsigned int u; float f; } v; v.u = ((unsigned int)s) << 16; return v.f;
}
__device__ __forceinline__ unsigned short f2b(float f) {
    union { float f; unsigned int u; } v; v.f = f;
    unsigned int r = v.u + 0x7fffu + ((v.u >> 16) & 1u);
    return (unsigned short)(r >> 16);
}
__device__ __forceinline__ unsigned short f2bt(float f) {   // truncating bf16
    union { float f; unsigned int u; } v; v.f = f;
    return (unsigned short)(v.u >> 16);
}
__device__ __forceinline__ void async_copy16(void* lds, const void* g) {
    __builtin_amdgcn_global_load_lds(
        (const __attribute__((address_space(1))) unsigned int*)g,
        (__attribute__((address_space(3))) unsigned int*)lds, 16, 0, 0);
}
__device__ __forceinline__ float frcp(float x) { return __builtin_amdgcn_rcpf(x); }
__device__ __forceinline__ float fsig(float x) { return frcp(1.f + __expf(-x)); }
__device__ __forceinline__ float ftanh_(float x) { return 2.f * fsig(2.f * x) - 1.f; }

// ---------- fused weight prep: transposes + casts + bias fold, one launch ----------
__global__ void k_prep(const float* W0, const float* W1, const float* W2, const float* Wa,
                       const float* Wih, const float* Whh, const float* bih, const float* bhh,
                       unsigned short* w0t, unsigned short* w1t, unsigned short* w2t,
                       unsigned short* watb, unsigned short* wihb, unsigned char* whh8,
                       float* b3) {
    int b = blockIdx.x, tid = threadIdx.x;
    if (b < 320) {                       // w0t[j][k] = W0[k][j], Kd=320
        int idx = b * 256 + tid; int j = idx / 320, k = idx % 320;
        w0t[idx] = f2b(W0[k * 256 + j]);
    } else if (b < 576) {
        int idx = (b - 320) * 256 + tid; int j = idx >> 8, k = idx & 255;
        w1t[idx] = f2b(W1[k * 256 + j]);
    } else if (b < 832) {
        int idx = (b - 576) * 256 + tid; int j = idx >> 8, k = idx & 255;
        w2t[idx] = f2b(W2[k * 256 + j]);
    } else if (b < 1088) {
        int idx = (b - 832) * 256 + tid; int j = idx >> 8, k = idx & 255;
        watb[idx] = f2b(Wa[k * 256 + j]);
    } else if (b < 1856) {               // Wih bf16 cast (row-major, is already [j][k])
        int i = (b - 1088) * 256 + tid;
        wihb[i] = f2b(Wih[i]);
    } else if (b < 2048) {               // Whh fp8 e4m3 cast
        int i = (b - 1856) * 256 + tid;
        float4 w = *(const float4*)(Whh + (size_t)i * 4);
        int pk = __builtin_amdgcn_cvt_pk_fp8_f32(w.x, w.y, 0, false);
        pk = __builtin_amdgcn_cvt_pk_fp8_f32(w.z, w.w, pk, true);
        ((int*)whh8)[i] = pk;
    } else {                             // b3 = bih + bhh
        int i = (b - 2048) * 256 + tid;
        if (i < 768) b3[i] = bih[i] + bhh[i];
    }
}

// dense t=0 read: r0 = p_init @ M, cc0 = p_init . C
__global__ void k_r0(const float* M, const float* C, const float* p0,
                     float* r0, float* cc0) {
    int n = blockIdx.x; int tid = threadIdx.x;
    __shared__ float pinit[L_];
    __shared__ float red[256];
    __shared__ int nz;
    if (tid == 0) nz = 0;
    __syncthreads();
    float p = p0[n * L_ + tid];
    if (p != 0.f) atomicAdd(&nz, 1);
    pinit[tid] = p;
    __syncthreads();
    if (tid == 0 && nz == 0) pinit[0] = 1.0f;
    __syncthreads();
    float acc = 0.f;
    for (int l = 0; l < L_; ++l) {
        float s = pinit[l];
        if (s != 0.f) acc += s * M[((size_t)n * L_ + l) * H_ + tid];
    }
    r0[n * H_ + tid] = acc;
    red[tid] = pinit[tid] * C[n * L_ + tid];
    __syncthreads();
    for (int s = 128; s > 0; s >>= 1) { if (tid < s) red[tid] += red[tid + s]; __syncthreads(); }
    if (tid == 0) cc0[n] = red[0];
}
__global__ void k_cc(const float* C, const int* act, const float* cc0, float* cc) {
    int idx = blockIdx.x * 256 + threadIdx.x;
    int t = idx / N_, n = idx % N_;
    cc[idx] = (t == 0) ? cc0[n] : C[n * L_ + act[(t - 1) * N_ + n]];
}
// xin[m][0:64]=cond, [64:320]=r (gather / dense t=0), bf16
__global__ void k_xin(const float* cond, const float* M, const float* r0,
                      const int* act, unsigned short* xin) {
    int idx = blockIdx.x * 256 + threadIdx.x;   // m*320+j
    int m = idx / 320, j = idx % 320;
    int t = m / N_, n = m % N_;
    float v;
    if (j < COND_) v = cond[(size_t)m * COND_ + j];
    else {
        int h = j - COND_;
        v = (t == 0) ? r0[n * H_ + h]
                     : M[((size_t)n * L_ + act[(t - 1) * N_ + n]) * H_ + h];
    }
    xin[(size_t)m * 320 + j] = f2b(v);
}

// ---------- bf16 MFMA GEMM ----------
// TRANS=0: D[m][j] = act(A@Bt^T+bias), operand-swapped MFMA so each thread
//          stores 4 contiguous cols (ushort4).
// TRANS=1: stores D transposed per t-slab: G[(t*768 + j)*256 + n] (for gi).
template<int RELU, int TRANS>
__global__ __launch_bounds__(256, 2)
void k_gemm(const unsigned short* A, const unsigned short* Bt, const float* bias,
            unsigned short* D, int Ndim, int Kdim) {
    __shared__ __align__(16) unsigned short sA[128 * 64];
    __shared__ __align__(16) unsigned short sB[128 * 64];
    int tid = threadIdx.x;
    int m0 = blockIdx.y * 128, n0 = blockIdx.x * 128;
    int wave = tid >> 6, lane = tid & 63;
    int wm = (wave & 1) * 64, wn = (wave >> 1) * 64;
    int lrow = lane & 15, quad = lane >> 4;
    f32x4 acc[4][4] = {};
    int kIters = Kdim / 64;
    for (int kt = 0; kt < kIters; ++kt) {
        __syncthreads();
        #pragma unroll
        for (int i = 0; i < 4; ++i) {
            int q = i * 256 + tid;
            int row = q >> 3, c = q & 7, sc = c ^ (row & 7);
            async_copy16((char*)sA + q * 16,
                         A + (size_t)(m0 + row) * Kdim + kt * 64 + sc * 8);
        }
        #pragma unroll
        for (int i = 0; i < 4; ++i) {
            int q = i * 256 + tid;
            int row = q >> 3, c = q & 7, sc = c ^ (row & 7);
            async_copy16((char*)sB + q * 16,
                         Bt + (size_t)(n0 + row) * Kdim + kt * 64 + sc * 8);
        }
        __syncthreads();
        #pragma unroll
        for (int kc = 0; kc < 2; ++kc) {
            bf8_t af[4], bfr[4];
            #pragma unroll
            for (int mt = 0; mt < 4; ++mt) {
                int row = wm + mt * 16 + lrow;
                int phys = (kc * 4 + quad) ^ (row & 7);
                af[mt] = *(const bf8_t*)(sA + row * 64 + phys * 8);
            }
            #pragma unroll
            for (int nt = 0; nt < 4; ++nt) {
                int row = wn + nt * 16 + lrow;
                int phys = (kc * 4 + quad) ^ (row & 7);
                bfr[nt] = *(const bf8_t*)(sB + row * 64 + phys * 8);
            }
            #pragma unroll
            for (int mt = 0; mt < 4; ++mt)
                #pragma unroll
                for (int nt = 0; nt < 4; ++nt) {
                    if (TRANS)
                        acc[mt][nt] = __builtin_amdgcn_mfma_f32_16x16x32_bf16(
                            af[mt], bfr[nt], acc[mt][nt], 0, 0, 0);
                    else
                        acc[mt][nt] = __builtin_amdgcn_mfma_f32_16x16x32_bf16(
                            bfr[nt], af[mt], acc[mt][nt], 0, 0, 0);
                }
        }
    }
    if (TRANS == 0) {
        // acc[mt][nt][r]: row(quad,r) = col j, col(lrow) = row m
        #pragma unroll
        for (int nt = 0; nt < 4; ++nt) {
            int jb = n0 + wn + nt * 16 + quad * 4;
            float4 bv = *(const float4*)(bias + jb);
            #pragma unroll
            for (int mt = 0; mt < 4; ++mt) {
                int m = m0 + wm + mt * 16 + lrow;
                float v0 = acc[mt][nt][0] + bv.x;
                float v1 = acc[mt][nt][1] + bv.y;
                float v2 = acc[mt][nt][2] + bv.z;
                float v3 = acc[mt][nt][3] + bv.w;
                if (RELU) {
                    v0 = v0 > 0.f ? v0 : 0.f; v1 = v1 > 0.f ? v1 : 0.f;
                    v2 = v2 > 0.f ? v2 : 0.f; v3 = v3 > 0.f ? v3 : 0.f;
                }
                ushort4 s; s.x = f2b(v0); s.y = f2b(v1); s.z = f2b(v2); s.w = f2b(v3);
                *(ushort4*)(D + (size_t)m * Ndim + jb) = s;
            }
        }
    } else {
        // acc[mt][nt][r]: row(quad,r) = m (=t*256+n), col(lrow) = j
        int t = m0 >> 8;
        #pragma unroll
        for (int nt = 0; nt < 4; ++nt) {
            int j = n0 + wn + nt * 16 + lrow;
            float bv = bias[j];
            #pragma unroll
            for (int mt = 0; mt < 4; ++mt) {
                int nb = (m0 & 255) + wm + mt * 16 + quad * 4;
                ushort4 s;
                s.x = f2b(acc[mt][nt][0] + bv);
                s.y = f2b(acc[mt][nt][1] + bv);
                s.z = f2b(acc[mt][nt][2] + bv);
                s.w = f2b(acc[mt][nt][3] + bv);
                *(ushort4*)(D + ((size_t)t * 768 + j) * 256 + nb) = s;
            }
        }
    }
}

// ---------- phase B: sequential GRU ----------
// gi transposed layout [t][768][256]; W_hh fp8 register-resident.
#define HP8 272
#define HPB 272
__global__ __launch_bounds__(1024, 4)
void k_gru(const unsigned short* gi, const unsigned char* Whh8,
           const float* h0, unsigned short* h_sbf) {
    int n0 = blockIdx.x * 16;
    int tid = threadIdx.x, wave = tid >> 6, lane = tid & 63;
    int lj = lane & 15, quad = lane >> 4;
    __shared__ __align__(16) unsigned char gibuf[2][768 * 32];    // 49152 B
    __shared__ __align__(16) unsigned char  h8b[2][16 * HP8];     // 8704 B
    __shared__ __align__(16) unsigned short hbb[2][16 * HPB];     // 17408 B
    __shared__ float guard[1600];                                  // LDS pad > 80 KB: 1 block/CU
    if (tid < 1600) guard[tid] = 0.f;
    int j = wave * 16 + lj;              // this lane's gate column (0..255)
    // register-resident W_hh fp8 fragments
    long wf[3][8];
    #pragma unroll
    for (int g = 0; g < 3; ++g)
        #pragma unroll
        for (int kc = 0; kc < 8; ++kc)
            wf[g][kc] = *(const long*)(Whh8 + (size_t)(g * 256 + j) * 256 + kc * 32 + quad * 8);
    float hreg[4];
    #pragma unroll
    for (int r = 0; r < 4; ++r)
        hreg[r] = h0[(size_t)(n0 + quad * 4 + r) * 256 + j];
    // stage h0 -> h8b[0] (fp8)
    {
        int n = tid >> 6, c = (tid & 63) * 4;
        float4 hv = *(const float4*)(h0 + (size_t)(n0 + n) * 256 + c);
        int pk = __builtin_amdgcn_cvt_pk_fp8_f32(hv.x, hv.y, 0, false);
        pk = __builtin_amdgcn_cvt_pk_fp8_f32(hv.z, hv.w, pk, true);
        *(int*)(h8b[0] + n * HP8 + c) = pk;
    }
    // gi staging: chunk c -> row jr = c>>1, half = c&1, bank-swizzled n-group
    int c0 = tid, c1 = 1024 + tid;
    int jr0 = c0 >> 1, x0 = (jr0 >> 2) & 2, g80 = ((c0 & 1) * 2) ^ x0;
    int jr1 = c1 >> 1, x1 = (jr1 >> 2) & 2, g81 = ((c1 & 1) * 2) ^ x1;
    const unsigned short* gp0 = gi + (size_t)jr0 * 256 + n0 + g80 * 4;
    const unsigned short* gp1 = gi + (size_t)jr1 * 256 + n0 + g81 * 4;
    int lo0 = c0 * 16, lo1 = c1 * 16;
    async_copy16(gibuf[0] + lo0, gp0);
    if (tid < 512) async_copy16(gibuf[0] + lo1, gp1);
    // in-loop gi read base (swizzle-matched), gates at +0x2000/+0x4000
    int gbase = j * 32 + (quad ^ ((j >> 2) & 2)) * 8;
    int con = tid >> 6, coc = (tid & 63) * 4;      // copy-out mapping
    for (int t = 0; t < T_; ++t) {
        __syncthreads();
        // copy out h_{t-1} (coalesced 8 B/thread)
        if (t > 0) {
            long v = *(const long*)(&hbb[t & 1][con * HPB + coc]);
            *(long*)(h_sbf + ((size_t)(t - 1) * N_ + n0 + con) * 256 + coc) = v;
        }
        if (t + 1 < T_) {
            size_t toff = (size_t)(t + 1) * 768 * 256;
            async_copy16(gibuf[(t + 1) & 1] + lo0, gp0 + toff);
            if (tid < 512) async_copy16(gibuf[(t + 1) & 1] + lo1, gp1 + toff);
        }
        // gh = h @ Whh^T : fp8 MFMA
        f32x4 acc[3] = {};
        const unsigned char* hb = h8b[t & 1];
        #pragma unroll
        for (int kc = 0; kc < 8; ++kc) {
            long a = *(const long*)(hb + lj * HP8 + kc * 32 + quad * 8);
            #pragma unroll
            for (int g = 0; g < 3; ++g)
                acc[g] = __builtin_amdgcn_mfma_f32_16x16x32_fp8_fp8(a, wf[g][kc], acc[g], 0, 0, 0);
        }
        // gate math; gi reads: 3 x ds_read_b64 (4 rows each)
        const unsigned char* gb = gibuf[t & 1];
        long q0 = *(const long*)(gb + gbase);
        long q1 = *(const long*)(gb + gbase + 8192);
        long q2 = *(const long*)(gb + gbase + 16384);
        unsigned char* h8w = h8b[(t + 1) & 1];
        unsigned short* hbw = hbb[(t + 1) & 1];
        #pragma unroll
        for (int r = 0; r < 4; ++r) {
            int n = quad * 4 + r;
            float gir = b2f((unsigned short)(q0 >> (16 * r)));
            float giz = b2f((unsigned short)(q1 >> (16 * r)));
            float gin = b2f((unsigned short)(q2 >> (16 * r)));
            float rg = fsig(gir + acc[0][r]);
            float z  = fsig(giz + acc[1][r]);
            float nn = ftanh_(gin + rg * acc[2][r]);
            float h  = nn + z * (hreg[r] - nn);
            hreg[r] = h;
            int pk = __builtin_amdgcn_cvt_pk_fp8_f32(h, h, 0, false);
            h8w[n * HP8 + j] = (unsigned char)pk;
            hbw[n * HPB + j] = f2bt(h);
        }
    }
    __syncthreads();
    long v = *(const long*)(&hbb[0][con * HPB + coc]);
    *(long*)(h_sbf + ((size_t)127 * N_ + n0 + con) * 256 + coc) = v;
}

// ---------- phase C: per-n attention ----------
#define HPAD 280
__global__ __launch_bounds__(512, 2)
void k_attn(const float* Kmat, const unsigned short* kbf, const float* cc, float* out) {
    int n = blockIdx.x;
    int tid = threadIdx.x, wave = tid >> 6, lane = tid & 63;
    int lt = lane & 15, quad = lane >> 4;
    __shared__ __align__(16) unsigned short sK[128 * HPAD];
    int tg = wave * 16 + lt;
    bf8_t bfr[8];
    #pragma unroll
    for (int kc = 0; kc < 8; ++kc)
        bfr[kc] = *(const bf8_t*)(kbf + ((size_t)tg * N_ + n) * H_ + kc * 32 + quad * 8);
    f32x4 acc[16];
    #pragma unroll
    for (int i = 0; i < 16; ++i) acc[i] = (f32x4){0.f, 0.f, 0.f, 0.f};
    for (int half = 0; half < 2; ++half) {
        __syncthreads();
        for (int i = 0; i < 16; ++i) {
            int idx = i * 512 + tid;
            int row = idx >> 6, c4 = idx & 63;
            float4 v = *(const float4*)(Kmat + ((size_t)n * L_ + half * 128 + row) * H_ + c4 * 4);
            ushort4 s4; s4.x = f2bt(v.x); s4.y = f2bt(v.y); s4.z = f2bt(v.z); s4.w = f2bt(v.w);
            *(ushort4*)(sK + row * HPAD + c4 * 4) = s4;
        }
        __syncthreads();
        #pragma unroll
        for (int l2 = 0; l2 < 8; ++l2)
            #pragma unroll
            for (int kc = 0; kc < 8; ++kc) {
                bf8_t a = *(const bf8_t*)(sK + (l2 * 16 + lt) * HPAD + kc * 32 + quad * 8);
                acc[half * 8 + l2] = __builtin_amdgcn_mfma_f32_16x16x32_bf16(
                    a, bfr[kc], acc[half * 8 + l2], 0, 0, 0);
            }
    }
    float ccv = cc[(size_t)tg * N_ + n];
    float mx = -3.4e38f;
    #pragma unroll
    for (int i = 0; i < 16; ++i)
        #pragma unroll
        for (int r = 0; r < 4; ++r) { float v = acc[i][r] * ccv; acc[i][r] = v; mx = fmaxf(mx, v); }
    mx = fmaxf(mx, __shfl_xor(mx, 16, 64));
    mx = fmaxf(mx, __shfl_xor(mx, 32, 64));
    float sum = 0.f;
    #pragma unroll
    for (int i = 0; i < 16; ++i)
        #pragma unroll
        for (int r = 0; r < 4; ++r) { float e = __expf(acc[i][r] - mx); acc[i][r] = e; sum += e; }
    sum += __shfl_xor(sum, 16, 64);
    sum += __shfl_xor(sum, 32, 64);
    float inv = frcp(sum);
    float* pbuf = (float*)sK;
    for (int half = 0; half < 2; ++half) {
        __syncthreads();
        if ((wave >> 2) == half) {
            int trow = (wave & 3) * 16 + lt;
            #pragma unroll
            for (int i = 0; i < 16; ++i)
                #pragma unroll
                for (int r = 0; r < 4; ++r)
                    pbuf[trow * 260 + i * 16 + quad * 4 + r] = acc[i][r] * inv;
        }
        __syncthreads();
        for (int i = 0; i < 16; ++i) {
            int idx = i * 512 + tid;
            int trow = idx >> 7, c2 = idx & 127;
            float2 v = *(const float2*)(pbuf + trow * 260 + c2 * 2);
            int t = half * 64 + trow;
            *(float2*)(out + ((size_t)t * N_ + n) * 770 + 258 + c2 * 2) = v;
        }
    }
}

// ---------- epilogue: a, v, h(fp32 expand), one-hot p ----------
__global__ void k_vah(const unsigned short* h_sbf, const float* Wc, const float* bc,
                      const int* act, float* out) {
    int gw = blockIdx.x * 4 + (threadIdx.x >> 6);   // row t*N+n
    int lane = threadIdx.x & 63;
    const unsigned short* hrow = h_sbf + (size_t)gw * 256;
    float* orow = out + (size_t)gw * 770;
    float4 wv = *(const float4*)(Wc + lane * 4);
    ushort4 hv = *(const ushort4*)(hrow + lane * 4);
    float h0f = b2f(hv.x), h1f = b2f(hv.y), h2f = b2f(hv.z), h3f = b2f(hv.w);
    float s = h0f * wv.x + h1f * wv.y + h2f * wv.z + h3f * wv.w;
    *(float2*)(orow + 2 + lane * 4) = make_float2(h0f, h1f);
    *(float2*)(orow + 4 + lane * 4) = make_float2(h2f, h3f);
    int a = act[gw];
    #pragma unroll
    for (int i = 0; i < 4; ++i) {
        int l = i * 64 + lane;
        orow[514 + l] = (l == a) ? 1.f : 0.f;
    }
    #pragma unroll
    for (int off = 32; off; off >>= 1) s += __shfl_down(s, off, 64);
    if (lane == 0) {
        orow[1] = s + bc[0];
        orow[0] = (float)a;
    }
}

extern "C" void kernel_launch(void* const* d_in, const int* in_sizes, int n_in,
                              void* d_out, int out_size, void* d_ws, size_t ws_size,
                              hipStream_t stream) {
    (void)in_sizes; (void)n_in; (void)out_size; (void)ws_size;
    const float* cond = (const float*)d_in[0];
    const float* M    = (const float*)d_in[1];
    const float* Km   = (const float*)d_in[2];
    const float* C    = (const float*)d_in[3];
    const float* h0   = (const float*)d_in[4];
    const float* p0   = (const float*)d_in[5];
    const float* W0   = (const float*)d_in[6];
    const float* b0   = (const float*)d_in[7];
    const float* W1   = (const float*)d_in[8];
    const float* b1   = (const float*)d_in[9];
    const float* W2   = (const float*)d_in[10];
    const float* b2   = (const float*)d_in[11];
    const float* Wih  = (const float*)d_in[12];
    const float* Whh  = (const float*)d_in[13];
    const float* bih  = (const float*)d_in[14];
    const float* bhh  = (const float*)d_in[15];
    const float* Wa   = (const float*)d_in[16];
    const float* ba   = (const float*)d_in[17];
    const float* Wc   = (const float*)d_in[18];
    const float* bc   = (const float*)d_in[19];
    const int*   act  = (const int*)d_in[20];
    float* out = (float*)d_out;
    char* ws = (char*)d_ws;

    size_t o_xin  = 0;                       // 32768*320*2
    size_t o_actA = 20971520;
    size_t o_actB = 37748736;
    size_t o_gi   = 54525952;                // [t][768][256] u16
    size_t o_w0t  = 104857600;
    size_t o_w1t  = o_w0t + 163840;
    size_t o_w2t  = o_w1t + 131072;
    size_t o_wih  = o_w2t + 131072;
    size_t o_wat  = o_wih + 393216;
    size_t o_whh8 = o_wat + 131072;
    size_t o_r0   = o_whh8 + 393216;
    size_t o_cc0  = o_r0 + 262144;
    size_t o_cc   = o_cc0 + 1024;
    size_t o_b3   = o_cc + 131072;           // own slot (k_prep writes it early)
    size_t o_hsbf = o_actB;                  // reuse
    size_t o_kbf  = o_actA;                  // reuse

    unsigned short* xin  = (unsigned short*)(ws + o_xin);
    unsigned short* actA = (unsigned short*)(ws + o_actA);
    unsigned short* actB = (unsigned short*)(ws + o_actB);
    unsigned short* gi   = (unsigned short*)(ws + o_gi);
    unsigned short* w0t  = (unsigned short*)(ws + o_w0t);
    unsigned short* w1t  = (unsigned short*)(ws + o_w1t);
    unsigned short* w2t  = (unsigned short*)(ws + o_w2t);
    unsigned short* wihb = (unsigned short*)(ws + o_wih);
    unsigned short* watb = (unsigned short*)(ws + o_wat);
    unsigned char*  whh8 = (unsigned char*)(ws + o_whh8);
    float* r0  = (float*)(ws + o_r0);
    float* cc0 = (float*)(ws + o_cc0);
    float* cc  = (float*)(ws + o_cc);
    float* b3  = (float*)(ws + o_b3);
    unsigned short* hsbf = (unsigned short*)(ws + o_hsbf);
    unsigned short* kbf  = (unsigned short*)(ws + o_kbf);

    k_prep<<<2051, 256, 0, stream>>>(W0, W1, W2, Wa, Wih, Whh, bih, bhh,
                                     w0t, w1t, w2t, watb, wihb, whh8, b3);
    k_r0<<<256, 256, 0, stream>>>(M, C, p0, r0, cc0);
    k_cc<<<128, 256, 0, stream>>>(C, act, cc0, cc);
    k_xin<<<40960, 256, 0, stream>>>(cond, M, r0, act, xin);
    // MLP chain + gi (gi stored transposed [t][j][n])
    k_gemm<1,0><<<dim3(2, 256), 256, 0, stream>>>(xin,  w0t,  b0, actA, 256, 320);
    k_gemm<1,0><<<dim3(2, 256), 256, 0, stream>>>(actA, w1t,  b1, actB, 256, 256);
    k_gemm<1,0><<<dim3(2, 256), 256, 0, stream>>>(actB, w2t,  b2, actA, 256, 256);
    k_gemm<0,1><<<dim3(6, 256), 256, 0, stream>>>(actA, wihb, b3, gi,   768, 256);
    // sequential GRU
    k_gru<<<16, 1024, 0, stream>>>(gi, whh8, h0, hsbf);
    // k = h @ Wa + ba
    k_gemm<0,0><<<dim3(2, 256), 256, 0, stream>>>(hsbf, watb, ba, kbf, 256, 256);
    // epilogue
    k_vah<<<8192, 256, 0, stream>>>(hsbf, Wc, bc, act, out);
    k_attn<<<256, 512, 0, stream>>>(Km, kbf, cc, out);
}

// Round 4
// 578.452 us; speedup vs baseline: 1.1355x; 1.1355x over previous
//
#include <hip/hip_runtime.h>
#include <hip/hip_bf16.h>

#define T_ 128
#define N_ 256
#define L_ 256
#define H_ 256
#define COND_ 64

typedef __bf16 bf8_t __attribute__((ext_vector_type(8)));
typedef float f32x4 __attribute__((ext_vector_type(4)));

__device__ __forceinline__ float b2f(unsigned short s) {
    union { unsigned int u; float f; } v; v.u = ((unsigned int)s) << 16; return v.f;
}
__device__ __forceinline__ unsigned short f2b(float f) {
    union { float f; unsigned int u; } v; v.f = f;
    unsigned int r = v.u + 0x7fffu + ((v.u >> 16) & 1u);
    return (unsigned short)(r >> 16);
}
__device__ __forceinline__ unsigned short f2bt(float f) {   // truncating bf16
    union { float f; unsigned int u; } v; v.f = f;
    return (unsigned short)(v.u >> 16);
}
__device__ __forceinline__ void async_copy16(void* lds, const void* g) {
    __builtin_amdgcn_global_load_lds(
        (const __attribute__((address_space(1))) unsigned int*)g,
        (__attribute__((address_space(3))) unsigned int*)lds, 16, 0, 0);
}
__device__ __forceinline__ float frcp(float x) { return __builtin_amdgcn_rcpf(x); }
__device__ __forceinline__ float fsig(float x) { return frcp(1.f + __expf(-x)); }
__device__ __forceinline__ float ftanh_(float x) { return 2.f * fsig(2.f * x) - 1.f; }

// ---------- fused weight prep ----------
__global__ void k_prep(const float* W0, const float* W1, const float* W2, const float* Wa,
                       const float* Wih, const float* Whh, const float* bih, const float* bhh,
                       unsigned short* w0t, unsigned short* w1t, unsigned short* w2t,
                       unsigned short* watb, unsigned short* wihb, unsigned char* whh8,
                       float* b3) {
    int b = blockIdx.x, tid = threadIdx.x;
    if (b < 320) {
        int idx = b * 256 + tid; int j = idx / 320, k = idx % 320;
        w0t[idx] = f2b(W0[k * 256 + j]);
    } else if (b < 576) {
        int idx = (b - 320) * 256 + tid; int j = idx >> 8, k = idx & 255;
        w1t[idx] = f2b(W1[k * 256 + j]);
    } else if (b < 832) {
        int idx = (b - 576) * 256 + tid; int j = idx >> 8, k = idx & 255;
        w2t[idx] = f2b(W2[k * 256 + j]);
    } else if (b < 1088) {
        int idx = (b - 832) * 256 + tid; int j = idx >> 8, k = idx & 255;
        watb[idx] = f2b(Wa[k * 256 + j]);
    } else if (b < 1856) {
        int i = (b - 1088) * 256 + tid;
        wihb[i] = f2b(Wih[i]);
    } else if (b < 2048) {
        int i = (b - 1856) * 256 + tid;
        float4 w = *(const float4*)(Whh + (size_t)i * 4);
        int pk = __builtin_amdgcn_cvt_pk_fp8_f32(w.x, w.y, 0, false);
        pk = __builtin_amdgcn_cvt_pk_fp8_f32(w.z, w.w, pk, true);
        ((int*)whh8)[i] = pk;
    } else {
        int i = (b - 2048) * 256 + tid;
        if (i < 768) b3[i] = bih[i] + bhh[i];
    }
}

// dense t=0 read: r0 = p_init @ M, cc0 = p_init . C
__global__ void k_r0(const float* M, const float* C, const float* p0,
                     float* r0, float* cc0) {
    int n = blockIdx.x; int tid = threadIdx.x;
    __shared__ float pinit[L_];
    __shared__ float red[256];
    __shared__ int nz;
    if (tid == 0) nz = 0;
    __syncthreads();
    float p = p0[n * L_ + tid];
    if (p != 0.f) atomicAdd(&nz, 1);
    pinit[tid] = p;
    __syncthreads();
    if (tid == 0 && nz == 0) pinit[0] = 1.0f;
    __syncthreads();
    float acc = 0.f;
    for (int l = 0; l < L_; ++l) {
        float s = pinit[l];
        if (s != 0.f) acc += s * M[((size_t)n * L_ + l) * H_ + tid];
    }
    r0[n * H_ + tid] = acc;
    red[tid] = pinit[tid] * C[n * L_ + tid];
    __syncthreads();
    for (int s = 128; s > 0; s >>= 1) { if (tid < s) red[tid] += red[tid + s]; __syncthreads(); }
    if (tid == 0) cc0[n] = red[0];
}
__global__ void k_cc(const float* C, const int* act, const float* cc0, float* cc) {
    int idx = blockIdx.x * 256 + threadIdx.x;
    int t = idx / N_, n = idx % N_;
    cc[idx] = (t == 0) ? cc0[n] : C[n * L_ + act[(t - 1) * N_ + n]];
}
// xin[m][0:64]=cond, [64:320]=r
__global__ void k_xin(const float* cond, const float* M, const float* r0,
                      const int* act, unsigned short* xin) {
    int idx = blockIdx.x * 256 + threadIdx.x;
    int m = idx / 320, j = idx % 320;
    int t = m / N_, n = m % N_;
    float v;
    if (j < COND_) v = cond[(size_t)m * COND_ + j];
    else {
        int h = j - COND_;
        v = (t == 0) ? r0[n * H_ + h]
                     : M[((size_t)n * L_ + act[(t - 1) * N_ + n]) * H_ + h];
    }
    xin[(size_t)m * 320 + j] = f2b(v);
}

// ---------- bf16 MFMA GEMM: D[m][j] = act(A@Bt^T+bias), vectorized stores ----------
template<int RELU>
__global__ __launch_bounds__(256, 2)
void k_gemm(const unsigned short* A, const unsigned short* Bt, const float* bias,
            unsigned short* D, int Ndim, int Kdim) {
    __shared__ __align__(16) unsigned short sA[128 * 64];
    __shared__ __align__(16) unsigned short sB[128 * 64];
    int tid = threadIdx.x;
    int m0 = blockIdx.y * 128, n0 = blockIdx.x * 128;
    int wave = tid >> 6, lane = tid & 63;
    int wm = (wave & 1) * 64, wn = (wave >> 1) * 64;
    int lrow = lane & 15, quad = lane >> 4;
    f32x4 acc[4][4] = {};
    int kIters = Kdim / 64;
    for (int kt = 0; kt < kIters; ++kt) {
        __syncthreads();
        #pragma unroll
        for (int i = 0; i < 4; ++i) {
            int q = i * 256 + tid;
            int row = q >> 3, c = q & 7, sc = c ^ (row & 7);
            async_copy16((char*)sA + q * 16,
                         A + (size_t)(m0 + row) * Kdim + kt * 64 + sc * 8);
        }
        #pragma unroll
        for (int i = 0; i < 4; ++i) {
            int q = i * 256 + tid;
            int row = q >> 3, c = q & 7, sc = c ^ (row & 7);
            async_copy16((char*)sB + q * 16,
                         Bt + (size_t)(n0 + row) * Kdim + kt * 64 + sc * 8);
        }
        __syncthreads();
        #pragma unroll
        for (int kc = 0; kc < 2; ++kc) {
            bf8_t af[4], bfr[4];
            #pragma unroll
            for (int mt = 0; mt < 4; ++mt) {
                int row = wm + mt * 16 + lrow;
                int phys = (kc * 4 + quad) ^ (row & 7);
                af[mt] = *(const bf8_t*)(sA + row * 64 + phys * 8);
            }
            #pragma unroll
            for (int nt = 0; nt < 4; ++nt) {
                int row = wn + nt * 16 + lrow;
                int phys = (kc * 4 + quad) ^ (row & 7);
                bfr[nt] = *(const bf8_t*)(sB + row * 64 + phys * 8);
            }
            #pragma unroll
            for (int mt = 0; mt < 4; ++mt)
                #pragma unroll
                for (int nt = 0; nt < 4; ++nt)
                    acc[mt][nt] = __builtin_amdgcn_mfma_f32_16x16x32_bf16(
                        bfr[nt], af[mt], acc[mt][nt], 0, 0, 0);
        }
    }
    // acc[mt][nt][r]: row(quad,r) = col j, col(lrow) = row m
    #pragma unroll
    for (int nt = 0; nt < 4; ++nt) {
        int jb = n0 + wn + nt * 16 + quad * 4;
        float4 bv = *(const float4*)(bias + jb);
        #pragma unroll
        for (int mt = 0; mt < 4; ++mt) {
            int m = m0 + wm + mt * 16 + lrow;
            float v0 = acc[mt][nt][0] + bv.x;
            float v1 = acc[mt][nt][1] + bv.y;
            float v2 = acc[mt][nt][2] + bv.z;
            float v3 = acc[mt][nt][3] + bv.w;
            if (RELU) {
                v0 = v0 > 0.f ? v0 : 0.f; v1 = v1 > 0.f ? v1 : 0.f;
                v2 = v2 > 0.f ? v2 : 0.f; v3 = v3 > 0.f ? v3 : 0.f;
            }
            ushort4 s; s.x = f2b(v0); s.y = f2b(v1); s.z = f2b(v2); s.w = f2b(v3);
            *(ushort4*)(D + (size_t)m * Ndim + jb) = s;
        }
    }
}

// ---------- phase B: sequential GRU ----------
// gi row-major [t][n][768]; W_hh fp8 register-resident as A-operand;
// operand-swapped MFMA -> thread owns (n=lj, j=wave*16+quad*4+r): vector LDS ops.
#define HP8 272
#define HPB 264
__global__ __launch_bounds__(1024, 4)
void k_gru(const unsigned short* gi, const unsigned char* Whh8,
           const float* h0, unsigned short* h_sbf) {
    int n0 = blockIdx.x * 16;
    int tid = threadIdx.x, wave = tid >> 6, lane = tid & 63;
    int lj = lane & 15, quad = lane >> 4;
    __shared__ __align__(16) unsigned char gibuf[2][16 * 1536];   // 49152 B
    __shared__ __align__(16) unsigned char  h8b[2][16 * HP8];     // 8704 B
    __shared__ __align__(16) unsigned short hbb[2][16 * HPB];     // 16896 B
    int j = wave * 16 + lj;              // wf row (A-operand m index)
    // register-resident W_hh fp8 fragments (A-frag: lane lj = row j, quad covers k)
    long wf[3][8];
    #pragma unroll
    for (int g = 0; g < 3; ++g)
        #pragma unroll
        for (int kc = 0; kc < 8; ++kc)
            wf[g][kc] = *(const long*)(Whh8 + (size_t)(g * 256 + j) * 256 + kc * 32 + quad * 8);
    int jb = wave * 16 + quad * 4;       // gate-col base owned in C-layout
    float hreg[4];
    {
        float4 hv = *(const float4*)(h0 + (size_t)(n0 + lj) * 256 + jb);
        hreg[0] = hv.x; hreg[1] = hv.y; hreg[2] = hv.z; hreg[3] = hv.w;
    }
    // stage h0 -> h8b[0] (fp8)
    {
        int n = tid >> 6, c = (tid & 63) * 4;
        float4 hv = *(const float4*)(h0 + (size_t)(n0 + n) * 256 + c);
        int pk = __builtin_amdgcn_cvt_pk_fp8_f32(hv.x, hv.y, 0, false);
        pk = __builtin_amdgcn_cvt_pk_fp8_f32(hv.z, hv.w, pk, true);
        *(int*)(h8b[0] + n * HP8 + c) = pk;
    }
    // gi staging: 1536 16-B chunks, XOR swizzle on chunk index (phys = q, logical c ^= row&7)
    int p0 = tid, p1 = 1024 + tid;
    int row0 = p0 / 96, c0 = (p0 % 96) ^ (row0 & 7);
    int row1 = p1 / 96, c1 = (p1 % 96) ^ (row1 & 7);
    const unsigned short* gp0 = gi + (size_t)(n0 + row0) * 768 + c0 * 8;
    const unsigned short* gp1 = gi + (size_t)(n0 + row1) * 768 + c1 * 8;
    int lo0 = p0 * 16, lo1 = p1 * 16;
    async_copy16(gibuf[0] + lo0, gp0);
    if (tid < 512) async_copy16(gibuf[0] + lo1, gp1);
    // in-loop gi read: chunk = lj*96 + wave*2 + quad/2 (gate g adds 32 chunks)
    int cbase = lj * 96 + wave * 2 + (quad >> 1);
    int gbase = ((cbase ^ (lj & 7)) * 16) + (quad & 1) * 8;
    int con = tid >> 6, coc = (tid & 63) * 4;
    for (int t = 0; t < T_; ++t) {
        __syncthreads();
        if (t > 0) {            // copy out h_{t-1}, coalesced 8 B/thread
            long v = *(const long*)(&hbb[t & 1][con * HPB + coc]);
            *(long*)(h_sbf + ((size_t)(t - 1) * N_ + n0 + con) * 256 + coc) = v;
        }
        if (t + 1 < T_) {
            size_t toff = (size_t)(t + 1) * N_ * 768;
            async_copy16(gibuf[(t + 1) & 1] + lo0, gp0 + toff);
            if (tid < 512) async_copy16(gibuf[(t + 1) & 1] + lo1, gp1 + toff);
        }
        // gh = Whh @ h^T : fp8 MFMA, A = wf (rows j), B = h (cols n)
        f32x4 acc[3] = {};
        const unsigned char* hb = h8b[t & 1];
        #pragma unroll
        for (int kc = 0; kc < 8; ++kc) {
            long a = *(const long*)(hb + lj * HP8 + kc * 32 + quad * 8);
            #pragma unroll
            for (int g = 0; g < 3; ++g)
                acc[g] = __builtin_amdgcn_mfma_f32_16x16x32_fp8_fp8(wf[g][kc], a, acc[g], 0, 0, 0);
        }
        // gate math: gi reads = 3 x ds_read_b64 (4 consecutive j)
        const unsigned char* gb = gibuf[t & 1];
        long q0 = *(const long*)(gb + gbase);
        long q1 = *(const long*)(gb + gbase + 512);
        long q2 = *(const long*)(gb + gbase + 1024);
        unsigned char* h8w = h8b[(t + 1) & 1];
        unsigned short* hbw = hbb[(t + 1) & 1];
        float hn[4];
        #pragma unroll
        for (int r = 0; r < 4; ++r) {
            float gir = b2f((unsigned short)(q0 >> (16 * r)));
            float giz = b2f((unsigned short)(q1 >> (16 * r)));
            float gin = b2f((unsigned short)(q2 >> (16 * r)));
            float rg = fsig(gir + acc[0][r]);
            float z  = fsig(giz + acc[1][r]);
            float nn = ftanh_(gin + rg * acc[2][r]);
            float h  = nn + z * (hreg[r] - nn);
            hreg[r] = h; hn[r] = h;
        }
        int pk = __builtin_amdgcn_cvt_pk_fp8_f32(hn[0], hn[1], 0, false);
        pk = __builtin_amdgcn_cvt_pk_fp8_f32(hn[2], hn[3], pk, true);
        *(int*)(h8w + lj * HP8 + jb) = pk;
        ushort4 h4; h4.x = f2bt(hn[0]); h4.y = f2bt(hn[1]); h4.z = f2bt(hn[2]); h4.w = f2bt(hn[3]);
        *(ushort4*)(hbw + lj * HPB + jb) = h4;
    }
    __syncthreads();
    long v = *(const long*)(&hbb[0][con * HPB + coc]);
    *(long*)(h_sbf + ((size_t)127 * N_ + n0 + con) * 256 + coc) = v;
}

// ---------- phase C: per-n attention ----------
#define HPAD 280
__global__ __launch_bounds__(512, 2)
void k_attn(const float* Kmat, const unsigned short* kbf, const float* cc, float* out) {
    int n = blockIdx.x;
    int tid = threadIdx.x, wave = tid >> 6, lane = tid & 63;
    int lt = lane & 15, quad = lane >> 4;
    __shared__ __align__(16) unsigned short sK[128 * HPAD];
    int tg = wave * 16 + lt;
    bf8_t bfr[8];
    #pragma unroll
    for (int kc = 0; kc < 8; ++kc)
        bfr[kc] = *(const bf8_t*)(kbf + ((size_t)tg * N_ + n) * H_ + kc * 32 + quad * 8);
    f32x4 acc[16];
    #pragma unroll
    for (int i = 0; i < 16; ++i) acc[i] = (f32x4){0.f, 0.f, 0.f, 0.f};
    for (int half = 0; half < 2; ++half) {
        __syncthreads();
        for (int i = 0; i < 16; ++i) {
            int idx = i * 512 + tid;
            int row = idx >> 6, c4 = idx & 63;
            float4 v = *(const float4*)(Kmat + ((size_t)n * L_ + half * 128 + row) * H_ + c4 * 4);
            ushort4 s4; s4.x = f2bt(v.x); s4.y = f2bt(v.y); s4.z = f2bt(v.z); s4.w = f2bt(v.w);
            *(ushort4*)(sK + row * HPAD + c4 * 4) = s4;
        }
        __syncthreads();
        #pragma unroll
        for (int l2 = 0; l2 < 8; ++l2)
            #pragma unroll
            for (int kc = 0; kc < 8; ++kc) {
                bf8_t a = *(const bf8_t*)(sK + (l2 * 16 + lt) * HPAD + kc * 32 + quad * 8);
                acc[half * 8 + l2] = __builtin_amdgcn_mfma_f32_16x16x32_bf16(
                    a, bfr[kc], acc[half * 8 + l2], 0, 0, 0);
            }
    }
    float ccv = cc[(size_t)tg * N_ + n];
    float mx = -3.4e38f;
    #pragma unroll
    for (int i = 0; i < 16; ++i)
        #pragma unroll
        for (int r = 0; r < 4; ++r) { float v = acc[i][r] * ccv; acc[i][r] = v; mx = fmaxf(mx, v); }
    mx = fmaxf(mx, __shfl_xor(mx, 16, 64));
    mx = fmaxf(mx, __shfl_xor(mx, 32, 64));
    float sum = 0.f;
    #pragma unroll
    for (int i = 0; i < 16; ++i)
        #pragma unroll
        for (int r = 0; r < 4; ++r) { float e = __expf(acc[i][r] - mx); acc[i][r] = e; sum += e; }
    sum += __shfl_xor(sum, 16, 64);
    sum += __shfl_xor(sum, 32, 64);
    float inv = frcp(sum);
    float* pbuf = (float*)sK;
    for (int half = 0; half < 2; ++half) {
        __syncthreads();
        if ((wave >> 2) == half) {
            int trow = (wave & 3) * 16 + lt;
            #pragma unroll
            for (int i = 0; i < 16; ++i)
                #pragma unroll
                for (int r = 0; r < 4; ++r)
                    pbuf[trow * 260 + i * 16 + quad * 4 + r] = acc[i][r] * inv;
        }
        __syncthreads();
        for (int i = 0; i < 16; ++i) {
            int idx = i * 512 + tid;
            int trow = idx >> 7, c2 = idx & 127;
            float2 v = *(const float2*)(pbuf + trow * 260 + c2 * 2);
            int t = half * 64 + trow;
            *(float2*)(out + ((size_t)t * N_ + n) * 770 + 258 + c2 * 2) = v;
        }
    }
}

// ---------- epilogue: a, v, h(fp32 expand), one-hot p ----------
__global__ void k_vah(const unsigned short* h_sbf, const float* Wc, const float* bc,
                      const int* act, float* out) {
    int gw = blockIdx.x * 4 + (threadIdx.x >> 6);
    int lane = threadIdx.x & 63;
    const unsigned short* hrow = h_sbf + (size_t)gw * 256;
    float* orow = out + (size_t)gw * 770;
    float4 wv = *(const float4*)(Wc + lane * 4);
    ushort4 hv = *(const ushort4*)(hrow + lane * 4);
    float h0f = b2f(hv.x), h1f = b2f(hv.y), h2f = b2f(hv.z), h3f = b2f(hv.w);
    float s = h0f * wv.x + h1f * wv.y + h2f * wv.z + h3f * wv.w;
    *(float2*)(orow + 2 + lane * 4) = make_float2(h0f, h1f);
    *(float2*)(orow + 4 + lane * 4) = make_float2(h2f, h3f);
    int a = act[gw];
    #pragma unroll
    for (int i = 0; i < 4; ++i) {
        int l = i * 64 + lane;
        orow[514 + l] = (l == a) ? 1.f : 0.f;
    }
    #pragma unroll
    for (int off = 32; off; off >>= 1) s += __shfl_down(s, off, 64);
    if (lane == 0) {
        orow[1] = s + bc[0];
        orow[0] = (float)a;
    }
}

extern "C" void kernel_launch(void* const* d_in, const int* in_sizes, int n_in,
                              void* d_out, int out_size, void* d_ws, size_t ws_size,
                              hipStream_t stream) {
    (void)in_sizes; (void)n_in; (void)out_size; (void)ws_size;
    const float* cond = (const float*)d_in[0];
    const float* M    = (const float*)d_in[1];
    const float* Km   = (const float*)d_in[2];
    const float* C    = (const float*)d_in[3];
    const float* h0   = (const float*)d_in[4];
    const float* p0   = (const float*)d_in[5];
    const float* W0   = (const float*)d_in[6];
    const float* b0   = (const float*)d_in[7];
    const float* W1   = (const float*)d_in[8];
    const float* b1   = (const float*)d_in[9];
    const float* W2   = (const float*)d_in[10];
    const float* b2   = (const float*)d_in[11];
    const float* Wih  = (const float*)d_in[12];
    const float* Whh  = (const float*)d_in[13];
    const float* bih  = (const float*)d_in[14];
    const float* bhh  = (const float*)d_in[15];
    const float* Wa   = (const float*)d_in[16];
    const float* ba   = (const float*)d_in[17];
    const float* Wc   = (const float*)d_in[18];
    const float* bc   = (const float*)d_in[19];
    const int*   act  = (const int*)d_in[20];
    float* out = (float*)d_out;
    char* ws = (char*)d_ws;

    size_t o_xin  = 0;
    size_t o_actA = 20971520;
    size_t o_actB = 37748736;
    size_t o_gi   = 54525952;                // [t][n][768] u16 row-major
    size_t o_w0t  = 104857600;
    size_t o_w1t  = o_w0t + 163840;
    size_t o_w2t  = o_w1t + 131072;
    size_t o_wih  = o_w2t + 131072;
    size_t o_wat  = o_wih + 393216;
    size_t o_whh8 = o_wat + 131072;
    size_t o_r0   = o_whh8 + 393216;
    size_t o_cc0  = o_r0 + 262144;
    size_t o_cc   = o_cc0 + 1024;
    size_t o_b3   = o_cc + 131072;
    size_t o_hsbf = o_actB;
    size_t o_kbf  = o_actA;

    unsigned short* xin  = (unsigned short*)(ws + o_xin);
    unsigned short* actA = (unsigned short*)(ws + o_actA);
    unsigned short* actB = (unsigned short*)(ws + o_actB);
    unsigned short* gi   = (unsigned short*)(ws + o_gi);
    unsigned short* w0t  = (unsigned short*)(ws + o_w0t);
    unsigned short* w1t  = (unsigned short*)(ws + o_w1t);
    unsigned short* w2t  = (unsigned short*)(ws + o_w2t);
    unsigned short* wihb = (unsigned short*)(ws + o_wih);
    unsigned short* watb = (unsigned short*)(ws + o_wat);
    unsigned char*  whh8 = (unsigned char*)(ws + o_whh8);
    float* r0  = (float*)(ws + o_r0);
    float* cc0 = (float*)(ws + o_cc0);
    float* cc  = (float*)(ws + o_cc);
    float* b3  = (float*)(ws + o_b3);
    unsigned short* hsbf = (unsigned short*)(ws + o_hsbf);
    unsigned short* kbf  = (unsigned short*)(ws + o_kbf);

    k_prep<<<2051, 256, 0, stream>>>(W0, W1, W2, Wa, Wih, Whh, bih, bhh,
                                     w0t, w1t, w2t, watb, wihb, whh8, b3);
    k_r0<<<256, 256, 0, stream>>>(M, C, p0, r0, cc0);
    k_cc<<<128, 256, 0, stream>>>(C, act, cc0, cc);
    k_xin<<<40960, 256, 0, stream>>>(cond, M, r0, act, xin);
    // MLP chain + gi (gi row-major [t][n][768])
    k_gemm<1><<<dim3(2, 256), 256, 0, stream>>>(xin,  w0t,  b0, actA, 256, 320);
    k_gemm<1><<<dim3(2, 256), 256, 0, stream>>>(actA, w1t,  b1, actB, 256, 256);
    k_gemm<1><<<dim3(2, 256), 256, 0, stream>>>(actB, w2t,  b2, actA, 256, 256);
    k_gemm<0><<<dim3(6, 256), 256, 0, stream>>>(actA, wihb, b3, gi,   768, 256);
    // sequential GRU
    k_gru<<<16, 1024, 0, stream>>>(gi, whh8, h0, hsbf);
    // k = h @ Wa + ba
    k_gemm<0><<<dim3(2, 256), 256, 0, stream>>>(hsbf, watb, ba, kbf, 256, 256);
    // epilogue
    k_vah<<<8192, 256, 0, stream>>>(hsbf, Wc, bc, act, out);
    k_attn<<<256, 512, 0, stream>>>(Km, kbf, cc, out);
}